// Round 12
// baseline (366.413 us; speedup 1.0000x reference)
//
#include <hip/hip_runtime.h>
#include <hip/hip_bf16.h>

typedef _Float16 half4_t __attribute__((ext_vector_type(4)));
typedef _Float16 half8 __attribute__((ext_vector_type(8)));
typedef float f32x4 __attribute__((ext_vector_type(4)));

#define BB 16
#define HH 64
#define WW2 64
#define CC 256

// ---------------------------------------------------------------------------
// Kernel S1: MEGA stage-1, 9280 blocks (bijective 8-way XCD swizzle, 9280/8=1160).
//   work    0..8191 : offset transpose; half=0 blocks ALSO sample sw in-block
//                     (offAT eliminated); half=1 blocks write offBT.
//   work 8192..9215 : depthwise 5x5 conv (validated ring version), partials out.
//   work 9216..9279 : Ww/Wh transpose -> f16 (32) + pw -> pf f16 (32).
// All three groups are data-independent -> co-scheduled in one launch.
// ---------------------------------------------------------------------------
__global__ __launch_bounds__(256) void k_stage1(
    const float* __restrict__ x, const float* __restrict__ off,
    const float* __restrict__ lw,
    const float* __restrict__ Ww, const float* __restrict__ Wh,
    const float* __restrict__ pw,
    _Float16* __restrict__ swb, _Float16* __restrict__ offBT,
    _Float16* __restrict__ cvb,
    _Float16* __restrict__ WwT, _Float16* __restrict__ WhT,
    _Float16* __restrict__ pf,
    float* __restrict__ sswp, float* __restrict__ scvp)
{
  __shared__ _Float16 tile[64][65];
  __shared__ _Float16 xr[64][68];
  __shared__ float red[4][64];

  const int work = (blockIdx.x & 7) * 1160 + (blockIdx.x >> 3);
  const int t = threadIdx.x;

  if (work < 8192) {
    // ---- offset transpose (+ fused sw sampling for half 0) ----
    const int st   = work & 63;          // y (half0) / offset-row (half1)
    const int cht  = (work >> 6) & 3;
    const int half = (work >> 8) & 1;
    const int b    = work >> 9;
    const int ch0 = half * 256 + cht * 64;
    const float* src = off + ((size_t)b * 512 + ch0) * 4096 + st * 64;
    const int sl = t & 63;
    #pragma unroll
    for (int p = 0; p < 16; p++) {
      int chl = (t >> 6) + p * 4;
      tile[chl][sl] = (_Float16)src[(size_t)chl * 4096 + sl];
    }

    if (half == 0) {
      // stage x row slice: xr[x][cl] = x[b, y=st, x, cht*64+cl]
      const float* xs_src = x + ((size_t)(b * 64 + st) * 64) * 256 + cht * 64;
      const int xrow = t >> 2;
      const int c16 = (t & 3) * 16;
      #pragma unroll
      for (int j = 0; j < 4; j++) {
        float4 v = *(const float4*)(xs_src + (size_t)xrow * 256 + c16 + j * 4);
        half4_t h = {(_Float16)v.x, (_Float16)v.y, (_Float16)v.z, (_Float16)v.w};
        *(half4_t*)(&xr[xrow][c16 + j * 4]) = h;
      }
      __syncthreads();

      // sample: thread = (xg, cl); 16 x's per thread
      const int cl = t & 63, xg = t >> 6;
      const int cg = cht * 64 + cl;
      _Float16* sp = swb + ((size_t)(b * 64 + st) * 64) * 256 + cg;
      float asw = 0.f;
      #pragma unroll
      for (int k = 0; k < 16; k++) {
        int xi = xg * 16 + k;
        float dx = (float)tile[cl][xi];
        float xs2 = (float)xi + dx;
        float xf = floorf(xs2);
        float wx = xs2 - xf;
        int xq = (int)xf;
        float v0 = (xq >= 0 && xq < 64) ? (float)xr[xq][cl] : 0.f;
        float v1 = (xq + 1 >= 0 && xq + 1 < 64) ? (float)xr[xq + 1][cl] : 0.f;
        float swv = (1.f - wx) * v0 + wx * v1;
        sp[(size_t)xi * 256] = (_Float16)swv;
        asw += swv;
      }
      red[xg][cl] = asw;
      __syncthreads();
      if (t < 64)
        sswp[((size_t)b * 64 + st) * 256 + cht * 64 + t] =
            red[0][t] + red[1][t] + red[2][t] + red[3][t];
    } else {
      __syncthreads();
      // write offBT pixel-major (validated round 3)
      #pragma unroll
      for (int p = 0; p < 2; p++) {
        int pl = (t >> 3) + p * 32;
        int c8 = (t & 7) * 8;
        half8 hv;
        #pragma unroll
        for (int r = 0; r < 8; r++) hv[r] = tile[c8 + r][pl];
        int s = st * 64 + pl;
        size_t pix = (size_t)b * 4096 + (s & 63) * 64 + (s >> 6);
        *(half8*)(offBT + pix * 256 + cht * 64 + c8) = hv;
      }
    }
  } else if (work < 9216) {
    // ---- depthwise 5x5 conv (validated ring version, partials out) ----
    const int w2 = work - 8192;
    const int b = w2 >> 6, y = w2 & 63;
    const int c = t;

    float wgt[25];
    #pragma unroll
    for (int q = 0; q < 25; q++) wgt[q] = lw[c * 25 + q];

    const float* xb = x + (size_t)b * HH * WW2 * CC + c;
    const float* rp[5];
    bool yv[5];
    #pragma unroll
    for (int ky = 0; ky < 5; ky++) {
      int yy = y + ky - 2;
      yv[ky] = (yy >= 0 && yy < HH);
      rp[ky] = xb + (size_t)(yv[ky] ? yy : 0) * WW2 * CC;
    }

    _Float16* cp = cvb + ((size_t)b * 4096 + y * 64) * CC + c;
    float acc5[5] = {0.f, 0.f, 0.f, 0.f, 0.f};
    float acv = 0.f;

    #pragma unroll 5
    for (int u = 0; u < 70; ++u) {
      acc5[(u + 2) % 5] = 0.f;
      if (u < 64) {
        float c0 = yv[0] ? rp[0][u * CC] : 0.f;
        float c1 = yv[1] ? rp[1][u * CC] : 0.f;
        float c2 = yv[2] ? rp[2][u * CC] : 0.f;
        float c3 = yv[3] ? rp[3][u * CC] : 0.f;
        float c4 = yv[4] ? rp[4][u * CC] : 0.f;
        #pragma unroll
        for (int kx = 0; kx < 5; kx++) {
          acc5[(u + 7 - kx) % 5] += wgt[0 + kx] * c0 + wgt[5 + kx] * c1 +
                                    wgt[10 + kx] * c2 + wgt[15 + kx] * c3 +
                                    wgt[20 + kx] * c4;
        }
      }
      int xi = u - 2;
      if (xi >= 0 && xi < 64) {
        float cv = acc5[(u + 3) % 5];
        cp[(size_t)xi * CC] = (_Float16)cv;
        acv += cv;
      }
    }
    scvp[((size_t)b * 64 + y) * 256 + c] = acv;
  } else {
    const int w3 = work - 9216;
    if (w3 < 32) {
      // ---- Ww/Wh transpose -> f16 [k][n] (validated k_pre branch) ----
      const int nt = w3 & 3, kt = (w3 >> 2) & 3, mat = w3 >> 4;
      const float* src = mat ? Wh : Ww;
      _Float16* dst = mat ? WhT : WwT;
      const int n0 = nt * 64, k0 = kt * 64;
      const int sl = t & 63;
      #pragma unroll
      for (int p = 0; p < 16; p++) {
        int chl = (t >> 6) + p * 4;
        tile[chl][sl] = (_Float16)src[(size_t)(n0 + chl) * 256 + k0 + sl];
      }
      __syncthreads();
      #pragma unroll
      for (int p = 0; p < 2; p++) {
        int pl = (t >> 3) + p * 32;
        int c8 = (t & 7) * 8;
        half8 hv;
        #pragma unroll
        for (int r = 0; r < 8; r++) hv[r] = tile[c8 + r][pl];
        *(half8*)(dst + (size_t)(k0 + pl) * 256 + n0 + c8) = hv;
      }
    } else {
      // ---- pw -> pf f16 ----
      int i = (w3 - 32) * 2048 + t * 8;
      float4 v0 = *(const float4*)(pw + i);
      float4 v1 = *(const float4*)(pw + i + 4);
      half8 h = {(_Float16)v0.x, (_Float16)v0.y, (_Float16)v0.z, (_Float16)v0.w,
                 (_Float16)v1.x, (_Float16)v1.y, (_Float16)v1.z, (_Float16)v1.w};
      *(half8*)(pf + i) = h;
    }
  }
}

// ---------------------------------------------------------------------------
// Kernel C: sh sampling (validated round 5; partials out instead of atomics).
// ---------------------------------------------------------------------------
__global__ __launch_bounds__(256) void k_col(
    const float* __restrict__ x, const _Float16* __restrict__ offBT,
    _Float16* __restrict__ shb, float* __restrict__ sshp)
{
  __shared__ _Float16 xc[HH * CC];      // [y][c]
  const int work = (blockIdx.x & 7) * 128 + (blockIdx.x >> 3);  // 1024 blocks
  const int b = work >> 6, xi = work & 63;
  const int t = threadIdx.x;
  const int c = t;

  #pragma unroll
  for (int p = 0; p < 16; p++) {
    int yy = p * 4 + (t >> 6);
    int c4 = (t & 63) * 4;
    float4 v = *(const float4*)(x + ((size_t)(b * HH + yy) * WW2 + xi) * CC + c4);
    half4_t h = {(_Float16)v.x, (_Float16)v.y, (_Float16)v.z, (_Float16)v.w};
    *(half4_t*)(xc + yy * CC + c4) = h;
  }
  __syncthreads();

  const _Float16* obt = offBT + ((size_t)(b * WW2 + xi) * HH) * CC + c;
  _Float16* hp = shb + ((size_t)(b * HH) * WW2 + xi) * CC + c;
  float ash = 0.f;
  #pragma unroll 8
  for (int yy = 0; yy < 64; yy++) {
    float dy = (float)obt[(size_t)yy * CC];
    float ys = (float)yy + dy;
    float yf = floorf(ys);
    float wy = ys - yf;
    int yq = (int)yf;
    float u0 = (yq >= 0 && yq < HH) ? (float)xc[yq * CC + c] : 0.f;
    float u1 = (yq + 1 >= 0 && yq + 1 < HH) ? (float)xc[(yq + 1) * CC + c] : 0.f;
    float shv = (1.f - wy) * u0 + wy * u1;
    hp[(size_t)yy * WW2 * CC] = (_Float16)shv;
    ash += shv;
  }
  sshp[((size_t)b * 64 + xi) * 256 + c] = ash;
}

// ---------------------------------------------------------------------------
// Kernel B: gating MLP; reduces the per-block partial sums (no atomics, no
// zeroing). Outputs gh[3][16][256] f16 + bcomb f32.
// ---------------------------------------------------------------------------
__global__ __launch_bounds__(256) void k_gate(
    const float* __restrict__ sswp, const float* __restrict__ sshp,
    const float* __restrict__ scvp,
    const float* __restrict__ Ww, const float* __restrict__ bw,
    const float* __restrict__ Wh, const float* __restrict__ bh,
    const float* __restrict__ blc,
    const float* __restrict__ fc1w, const float* __restrict__ fc1b,
    const float* __restrict__ fc2w, const float* __restrict__ fc2b,
    _Float16* __restrict__ gh, float* __restrict__ bcomb)
{
  __shared__ float sswl[CC], sshl[CC], avgl[CC], tl[64];
  const int b = blockIdx.x, tid = threadIdx.x;

  float s_sw = 0.f, s_sh = 0.f, s_cv = 0.f;
  for (int q = 0; q < 64; q++) {
    s_sw += sswp[((size_t)b * 64 + q) * 256 + tid];
    s_sh += sshp[((size_t)b * 64 + q) * 256 + tid];
    s_cv += scvp[((size_t)b * 64 + q) * 256 + tid];
  }
  sswl[tid] = s_sw;
  sshl[tid] = s_sh;
  __syncthreads();

  float acc = s_cv;
  for (int c = 0; c < CC; c++)
    acc += sswl[c] * Ww[tid * CC + c] + sshl[c] * Wh[tid * CC + c];
  avgl[tid] = acc * (1.f / (HH * WW2)) + bw[tid] + bh[tid] + blc[tid];
  __syncthreads();

  if (tid < 64) {
    float a = fc1b[tid];
    for (int o = 0; o < CC; o++) a += avgl[o] * fc1w[tid * CC + o];
    tl[tid] = 0.5f * a * (1.f + erff(a * 0.70710678118654752f));
  }
  __syncthreads();

  float g[3];
  #pragma unroll
  for (int j = 0; j < 3; j++) {
    float a = fc2b[tid * 3 + j];
    for (int k = 0; k < 64; k++) a += tl[k] * fc2w[(tid * 3 + j) * 64 + k];
    g[j] = a;
  }
  float m = fmaxf(g[0], fmaxf(g[1], g[2]));
  float e0 = expf(g[0] - m), e1 = expf(g[1] - m), e2 = expf(g[2] - m);
  float inv = 1.f / (e0 + e1 + e2);
  float a0 = e0 * inv, a1 = e1 * inv, a2 = e2 * inv;
  gh[(0 * BB + b) * CC + tid] = (_Float16)a0;
  gh[(1 * BB + b) * CC + tid] = (_Float16)a1;
  gh[(2 * BB + b) * CC + tid] = (_Float16)a2;
  bcomb[b * CC + tid] = a0 * bw[tid] + a1 * bh[tid] + a2 * blc[tid];
}

// ---------------------------------------------------------------------------
// Kernel M: build per-batch collapsed weights (validated round 7).
// ---------------------------------------------------------------------------
__global__ __launch_bounds__(256) void k_mats(
    const _Float16* __restrict__ pf, const _Float16* __restrict__ gh,
    const _Float16* __restrict__ WwT, const _Float16* __restrict__ WhT,
    const float* __restrict__ bcomb, const float* __restrict__ pb,
    _Float16* __restrict__ Bcat, float* __restrict__ bias_out)
{
  const int blk = (blockIdx.x & 7) * 16 + (blockIdx.x >> 3);  // 128 blocks
  const int ob = blk & 3;
  const int br = (blk >> 2) & 1;
  const int b  = blk >> 3;
  const int o0 = ob * 64;
  const int tid = threadIdx.x;
  const int wid = tid >> 6, l = tid & 63;
  const int n0 = wid * 64;             // k-column block
  const int lr = l & 15;
  const int kg = (l >> 4) * 8;
  const int jr = (l >> 4) * 4;

  const _Float16* WT  = br ? WhT : WwT;
  const _Float16* ghb = gh + (size_t)(br * BB + b) * CC;

  f32x4 acc[4][4];
  #pragma unroll
  for (int mi = 0; mi < 4; mi++)
    #pragma unroll
    for (int ni = 0; ni < 4; ni++) acc[mi][ni] = (f32x4){0.f, 0.f, 0.f, 0.f};

  #pragma unroll
  for (int ks = 0; ks < 8; ks++) {
    half8 gv = *(const half8*)(ghb + kg + ks * 32);
    half8 a[4], bbv[4];
    #pragma unroll
    for (int mi = 0; mi < 4; mi++)
      a[mi] = *(const half8*)(pf + (size_t)(o0 + mi * 16 + lr) * CC + kg + ks * 32) * gv;
    #pragma unroll
    for (int ni = 0; ni < 4; ni++)
      bbv[ni] = *(const half8*)(WT + (size_t)(n0 + ni * 16 + lr) * CC + kg + ks * 32);
    #pragma unroll
    for (int mi = 0; mi < 4; mi++)
      #pragma unroll
      for (int ni = 0; ni < 4; ni++)
        acc[mi][ni] = __builtin_amdgcn_mfma_f32_16x16x32_f16(a[mi], bbv[ni], acc[mi][ni], 0, 0, 0);
  }

  #pragma unroll
  for (int ni = 0; ni < 4; ni++) {
    int kcol = n0 + ni * 16 + lr;
    #pragma unroll
    for (int mi = 0; mi < 4; mi++) {
      #pragma unroll
      for (int j = 0; j < 4; j++) {
        int o = o0 + mi * 16 + jr + j;
        Bcat[((size_t)b * CC + o) * 512 + br * 256 + kcol] = (_Float16)acc[mi][ni][j];
      }
    }
  }

  if (br == 0) {
    int o_l = tid >> 2, part = tid & 3;
    const _Float16* pr = pf + (size_t)(o0 + o_l) * CC + part * 64;
    const float* bc = bcomb + b * CC + part * 64;
    float s = 0.f;
    #pragma unroll
    for (int i = 0; i < 8; i++) {
      half8 h = *(const half8*)(pr + i * 8);
      #pragma unroll
      for (int r = 0; r < 8; r++) s += (float)h[r] * bc[i * 8 + r];
    }
    s += __shfl_xor(s, 1);
    s += __shfl_xor(s, 2);
    if (part == 0) bias_out[b * CC + o0 + o_l] = s + pb[o0 + o_l];
  }
}

// ---------------------------------------------------------------------------
// Kernel G: single K=768 GEMM (validated round 7).
// ---------------------------------------------------------------------------
#define APAD 264
__global__ __launch_bounds__(256) void k_gemm(
    const _Float16* __restrict__ swb, const _Float16* __restrict__ shb,
    const _Float16* __restrict__ cvb, const _Float16* __restrict__ Bcat,
    const _Float16* __restrict__ pf, const _Float16* __restrict__ a2h,
    const float* __restrict__ bias_out, float* __restrict__ out)
{
  __shared__ _Float16 smem[64 * APAD];  // 33,792 B

  const int work = (blockIdx.x & 7) * 128 + (blockIdx.x >> 3);  // 1024 blocks
  const int r0 = work * 64;
  const int b = work >> 6;
  const int tid = threadIdx.x;
  const int wid = tid >> 6, l = tid & 63;
  const int n0 = wid * 64;
  const int lr = l & 15;
  const int kg = (l >> 4) * 8;
  const int jr = (l >> 4) * 4;

  const _Float16* bq = Bcat + ((size_t)b * CC + n0 + lr) * 512 + kg;

  f32x4 acc[4][4];
  #pragma unroll
  for (int mi = 0; mi < 4; mi++)
    #pragma unroll
    for (int ni = 0; ni < 4; ni++) acc[mi][ni] = (f32x4){0.f, 0.f, 0.f, 0.f};

  half8 st[8];
  // stage sw
  {
    const _Float16* g = swb + (size_t)r0 * CC;
    #pragma unroll
    for (int p = 0; p < 8; p++) st[p] = *(const half8*)(g + p * 2048 + tid * 8);
    #pragma unroll
    for (int p = 0; p < 8; p++) {
      int i = p * 2048 + tid * 8;
      *(half8*)(smem + (i >> 8) * APAD + (i & 255)) = st[p];
    }
  }
  __syncthreads();
  // prefetch sh (completes during sw phase)
  {
    const _Float16* g = shb + (size_t)r0 * CC;
    #pragma unroll
    for (int p = 0; p < 8; p++) st[p] = *(const half8*)(g + p * 2048 + tid * 8);
  }
  // ---- phase A: sw, ks 0..7 ----
  #pragma unroll
  for (int ks = 0; ks < 8; ks++) {
    half8 a[4], bbv[4];
    #pragma unroll
    for (int mi = 0; mi < 4; mi++)
      a[mi] = *(const half8*)(smem + (mi * 16 + lr) * APAD + kg + ks * 32);
    #pragma unroll
    for (int ni = 0; ni < 4; ni++)
      bbv[ni] = *(const half8*)(bq + (size_t)ni * 16 * 512 + ks * 32);
    #pragma unroll
    for (int mi = 0; mi < 4; mi++)
      #pragma unroll
      for (int ni = 0; ni < 4; ni++)
        acc[mi][ni] = __builtin_amdgcn_mfma_f32_16x16x32_f16(a[mi], bbv[ni], acc[mi][ni], 0, 0, 0);
  }
  __syncthreads();
  #pragma unroll
  for (int p = 0; p < 8; p++) {
    int i = p * 2048 + tid * 8;
    *(half8*)(smem + (i >> 8) * APAD + (i & 255)) = st[p];
  }
  __syncthreads();
  // prefetch cv (completes during sh phase)
  {
    const _Float16* g = cvb + (size_t)r0 * CC;
    #pragma unroll
    for (int p = 0; p < 8; p++) st[p] = *(const half8*)(g + p * 2048 + tid * 8);
  }
  // ---- phase B: sh, ks 0..7 (Bcat cols 256..511) ----
  #pragma unroll
  for (int ks = 0; ks < 8; ks++) {
    half8 a[4], bbv[4];
    #pragma unroll
    for (int mi = 0; mi < 4; mi++)
      a[mi] = *(const half8*)(smem + (mi * 16 + lr) * APAD + kg + ks * 32);
    #pragma unroll
    for (int ni = 0; ni < 4; ni++)
      bbv[ni] = *(const half8*)(bq + (size_t)ni * 16 * 512 + 256 + ks * 32);
    #pragma unroll
    for (int mi = 0; mi < 4; mi++)
      #pragma unroll
      for (int ni = 0; ni < 4; ni++)
        acc[mi][ni] = __builtin_amdgcn_mfma_f32_16x16x32_f16(a[mi], bbv[ni], acc[mi][ni], 0, 0, 0);
  }
  __syncthreads();
  #pragma unroll
  for (int p = 0; p < 8; p++) {
    int i = p * 2048 + tid * 8;
    *(half8*)(smem + (i >> 8) * APAD + (i & 255)) = st[p];
  }
  __syncthreads();
  // ---- phase C: cv, ks 0..7, B-frag = pf * a2 on the fly ----
  const _Float16* a2b = a2h + (size_t)b * CC;
  #pragma unroll
  for (int ks = 0; ks < 8; ks++) {
    half8 a2v = *(const half8*)(a2b + kg + ks * 32);
    half8 a[4], bbv[4];
    #pragma unroll
    for (int mi = 0; mi < 4; mi++)
      a[mi] = *(const half8*)(smem + (mi * 16 + lr) * APAD + kg + ks * 32);
    #pragma unroll
    for (int ni = 0; ni < 4; ni++)
      bbv[ni] = *(const half8*)(pf + (size_t)(n0 + ni * 16 + lr) * CC + kg + ks * 32) * a2v;
    #pragma unroll
    for (int mi = 0; mi < 4; mi++)
      #pragma unroll
      for (int ni = 0; ni < 4; ni++)
        acc[mi][ni] = __builtin_amdgcn_mfma_f32_16x16x32_f16(a[mi], bbv[ni], acc[mi][ni], 0, 0, 0);
  }

  // epilogue
  #pragma unroll
  for (int ni = 0; ni < 4; ni++) {
    int col = n0 + ni * 16 + lr;
    float bo = bias_out[b * CC + col];
    #pragma unroll
    for (int mi = 0; mi < 4; mi++) {
      #pragma unroll
      for (int j = 0; j < 4; j++) {
        size_t idx = (size_t)(r0 + mi * 16 + jr + j) * CC + col;
        out[idx] = acc[mi][ni][j] + bo;
      }
    }
  }
}

// ---------------------------------------------------------------------------
extern "C" void kernel_launch(void* const* d_in, const int* in_sizes, int n_in,
                              void* d_out, int out_size, void* d_ws, size_t ws_size,
                              hipStream_t stream)
{
  const float* x    = (const float*)d_in[0];
  const float* off  = (const float*)d_in[1];
  const float* Ww   = (const float*)d_in[2];
  const float* bw   = (const float*)d_in[3];
  const float* Wh   = (const float*)d_in[4];
  const float* bh   = (const float*)d_in[5];
  const float* lw   = (const float*)d_in[6];
  const float* blc  = (const float*)d_in[7];
  const float* fc1w = (const float*)d_in[8];
  const float* fc1b = (const float*)d_in[9];
  const float* fc2w = (const float*)d_in[10];
  const float* fc2b = (const float*)d_in[11];
  const float* pw   = (const float*)d_in[12];
  const float* pb   = (const float*)d_in[13];
  float* out = (float*)d_out;

  char* ws = (char*)d_ws;
  // ws regions (all disjoint in time; footprint == round-9-validated 138.6MB):
  //   shb   @  0   (32M)  written k_col, read k_gemm
  //   cvb   @ 32M  (32M)  written k_stage1(conv), read k_gemm
  //   offBT @ 64M  (32M)  written k_stage1(trans h1), read k_col
  //   swb   @ 96M  (32M)  written k_stage1(trans h0 fused sample), read k_gemm
  //   Bcat  @128M  ( 4M)  written k_mats; ALIASED first by partial sums
  //                       (sswp/sshp/scvp, consumed by k_gate before k_mats)
  //   pf/gh/bcomb/bias_out tail
  _Float16* shb   = (_Float16*)(ws + 0);
  _Float16* cvb   = (_Float16*)(ws + 33554432);
  _Float16* offBT = (_Float16*)(ws + 67108864);
  _Float16* swb   = (_Float16*)(ws + 100663296);
  _Float16* Bcat  = (_Float16*)(ws + 134217728);  // 4 MiB
  float* sswp     = (float*)(ws + 134217728);     // 1 MiB (aliases Bcat, dead by k_mats)
  float* sshp     = (float*)(ws + 135266304);     // 1 MiB
  float* scvp     = (float*)(ws + 136314880);     // 1 MiB
  _Float16* pf    = (_Float16*)(ws + 138412032);  // 131,072 B
  _Float16* gh    = (_Float16*)(ws + 138543104);  //  24,576 B
  float* bcomb    = (float*)(ws + 138567680);     //  16,384 B
  float* bias_out = (float*)(ws + 138584064);     //  16,384 B
  // d_out scratch (consumed by k_mats before k_gemm writes out):
  _Float16* WwT = (_Float16*)((char*)d_out + 0);        // 131,072 B
  _Float16* WhT = (_Float16*)((char*)d_out + 131072);   // 131,072 B

  k_stage1<<<9280, 256, 0, stream>>>(x, off, lw, Ww, Wh, pw,
                                     swb, offBT, cvb, WwT, WhT, pf,
                                     sswp, scvp);
  k_col<<<BB * WW2, 256, 0, stream>>>(x, offBT, shb, sshp);
  k_gate<<<BB, 256, 0, stream>>>(sswp, sshp, scvp, Ww, bw, Wh, bh, blc,
                                 fc1w, fc1b, fc2w, fc2b, gh, bcomb);
  k_mats<<<128, 256, 0, stream>>>(pf, gh, WwT, WhT, bcomb, pb, Bcat, bias_out);
  k_gemm<<<1024, 256, 0, stream>>>(swb, shb, cvb, Bcat, pf, gh + 2 * BB * CC,
                                   bias_out, out);
}

// Round 13
// 261.095 us; speedup vs baseline: 1.4034x; 1.4034x over previous
//
#include <hip/hip_runtime.h>
#include <hip/hip_bf16.h>

typedef _Float16 half4_t __attribute__((ext_vector_type(4)));
typedef _Float16 half8 __attribute__((ext_vector_type(8)));
typedef float f32x4 __attribute__((ext_vector_type(4)));

#define BB 16
#define HH 64
#define WW2 64
#define CC 256

// ---------------------------------------------------------------------------
// Kernel PRE: fused preamble, 112 blocks (validated round 8).
//   blocks  0..31 : Ww/Wh transpose -> f16 [k][n]
//   blocks 32..79 : zero the sums region (d_out scratch)
//   blocks 80..111: pw -> pf f16
// ---------------------------------------------------------------------------
__global__ __launch_bounds__(256) void k_pre(
    const float* __restrict__ Ww, const float* __restrict__ Wh,
    const float* __restrict__ pw,
    _Float16* __restrict__ WwT, _Float16* __restrict__ WhT,
    _Float16* __restrict__ pf, float* __restrict__ sums)
{
  __shared__ _Float16 tile[64][65];
  const int blk = blockIdx.x;
  const int t = threadIdx.x;

  if (blk < 32) {
    const int nt = blk & 3, kt = (blk >> 2) & 3, mat = blk >> 4;
    const float* src = mat ? Wh : Ww;
    _Float16* dst = mat ? WhT : WwT;
    const int n0 = nt * 64, k0 = kt * 64;
    const int sl = t & 63;
    #pragma unroll
    for (int p = 0; p < 16; p++) {
      int chl = (t >> 6) + p * 4;        // n-local
      tile[chl][sl] = (_Float16)src[(size_t)(n0 + chl) * 256 + k0 + sl];
    }
    __syncthreads();
    #pragma unroll
    for (int p = 0; p < 2; p++) {
      int pl = (t >> 3) + p * 32;        // k-local
      int c8 = (t & 7) * 8;              // n-local
      half8 hv;
      #pragma unroll
      for (int r = 0; r < 8; r++) hv[r] = tile[c8 + r][pl];
      *(half8*)(dst + (size_t)(k0 + pl) * 256 + n0 + c8) = hv;
    }
  } else if (blk < 80) {
    sums[(blk - 32) * 256 + t] = 0.f;    // 48*256 = 12288 floats
  } else {
    int i = (blk - 80) * 2048 + t * 8;   // 32*2048 = 65536 elems
    float4 v0 = *(const float4*)(pw + i);
    float4 v1 = *(const float4*)(pw + i + 4);
    half8 h = {(_Float16)v0.x, (_Float16)v0.y, (_Float16)v0.z, (_Float16)v0.w,
               (_Float16)v1.x, (_Float16)v1.y, (_Float16)v1.z, (_Float16)v1.w};
    *(half8*)(pf + i) = h;
  }
}

// ---------------------------------------------------------------------------
// Kernel TA: half-0 offset transpose + FUSED sw sampling (validated in round
// 11's mega-kernel, now a standalone kernel so it gets its own regalloc).
// Block = (b, cht, y). Offsets for (b,y, 64 ch) land in LDS [ch][x]; the
// matching x-row slice is staged [x][c]; sampling is pure-LDS. offAT and
// k_rows are eliminated entirely.
// ---------------------------------------------------------------------------
__global__ __launch_bounds__(256) void k_transA(
    const float* __restrict__ x, const float* __restrict__ off,
    _Float16* __restrict__ swb, float* __restrict__ ssw)
{
  __shared__ _Float16 tile[64][65];   // [ch_local][x] offsets
  __shared__ _Float16 xr[64][68];     // [x][ch_local]
  __shared__ float red[4][64];

  const int work = (blockIdx.x & 7) * 512 + (blockIdx.x >> 3);  // 4096 blocks
  const int st   = work & 63;          // y
  const int cht  = (work >> 6) & 3;
  const int b    = work >> 8;
  const int t = threadIdx.x;

  const int ch0 = cht * 64;
  const float* src = off + ((size_t)b * 512 + ch0) * 4096 + st * 64;
  const int sl = t & 63;
  #pragma unroll
  for (int p = 0; p < 16; p++) {
    int chl = (t >> 6) + p * 4;
    tile[chl][sl] = (_Float16)src[(size_t)chl * 4096 + sl];
  }

  // stage x row slice: xr[x][cl] = x[b, y=st, x, cht*64+cl]
  const float* xs_src = x + ((size_t)(b * 64 + st) * 64) * 256 + ch0;
  const int xrow = t >> 2;
  const int c16 = (t & 3) * 16;
  #pragma unroll
  for (int j = 0; j < 4; j++) {
    float4 v = *(const float4*)(xs_src + (size_t)xrow * 256 + c16 + j * 4);
    half4_t h = {(_Float16)v.x, (_Float16)v.y, (_Float16)v.z, (_Float16)v.w};
    *(half4_t*)(&xr[xrow][c16 + j * 4]) = h;
  }
  __syncthreads();

  // sample: thread = (xg, cl); 16 x's per thread
  const int cl = t & 63, xg = t >> 6;
  const int cg = ch0 + cl;
  _Float16* sp = swb + ((size_t)(b * 64 + st) * 64) * 256 + cg;
  float asw = 0.f;
  #pragma unroll
  for (int k = 0; k < 16; k++) {
    int xi = xg * 16 + k;
    float dx = (float)tile[cl][xi];
    float xs2 = (float)xi + dx;
    float xf = floorf(xs2);
    float wx = xs2 - xf;
    int xq = (int)xf;
    float v0 = (xq >= 0 && xq < 64) ? (float)xr[xq][cl] : 0.f;
    float v1 = (xq + 1 >= 0 && xq + 1 < 64) ? (float)xr[xq + 1][cl] : 0.f;
    float swv = (1.f - wx) * v0 + wx * v1;
    sp[(size_t)xi * 256] = (_Float16)swv;
    asw += swv;
  }
  red[xg][cl] = asw;
  __syncthreads();
  if (t < 64)
    atomicAdd(&ssw[b * CC + ch0 + t],
              red[0][t] + red[1][t] + red[2][t] + red[3][t]);
}

// ---------------------------------------------------------------------------
// Kernel TB: half-1 offset transpose -> offBT pixel-major (validated round 3).
// ---------------------------------------------------------------------------
__global__ __launch_bounds__(256) void k_transB(const float* __restrict__ off,
                                                _Float16* __restrict__ offBT)
{
  __shared__ _Float16 tile[64][65];
  const int work = (blockIdx.x & 7) * 512 + (blockIdx.x >> 3);  // 4096 blocks
  const int st   = work & 63;
  const int cht  = (work >> 6) & 3;
  const int b    = work >> 8;
  const int t = threadIdx.x;

  const int ch0 = 256 + cht * 64;
  const float* src = off + ((size_t)b * 512 + ch0) * 4096 + st * 64;
  const int sl = t & 63;
  #pragma unroll
  for (int p = 0; p < 16; p++) {
    int chl = (t >> 6) + p * 4;
    tile[chl][sl] = (_Float16)src[(size_t)chl * 4096 + sl];
  }
  __syncthreads();

  #pragma unroll
  for (int p = 0; p < 2; p++) {
    int pl = (t >> 3) + p * 32;
    int c8 = (t & 7) * 8;
    half8 hv;
    #pragma unroll
    for (int r = 0; r < 8; r++) hv[r] = tile[c8 + r][pl];
    int s = st * 64 + pl;
    size_t pix = (size_t)b * 4096 + (s & 63) * 64 + (s >> 6);
    *(half8*)(offBT + pix * 256 + cht * 64 + c8) = hv;
  }
}

// ---------------------------------------------------------------------------
// Kernel V: depthwise 5x5 conv (validated round-5/8 ring version).
// ---------------------------------------------------------------------------
__global__ __launch_bounds__(256) void k_conv(
    const float* __restrict__ x, const float* __restrict__ lw,
    _Float16* __restrict__ cvb, float* __restrict__ scv)
{
  const int work = (blockIdx.x & 7) * 128 + (blockIdx.x >> 3);  // 1024 blocks
  const int b = work >> 6, y = work & 63;
  const int c = threadIdx.x;

  float wgt[25];
  #pragma unroll
  for (int q = 0; q < 25; q++) wgt[q] = lw[c * 25 + q];

  const float* xb = x + (size_t)b * HH * WW2 * CC + c;
  const float* rp[5];
  bool yv[5];
  #pragma unroll
  for (int ky = 0; ky < 5; ky++) {
    int yy = y + ky - 2;
    yv[ky] = (yy >= 0 && yy < HH);
    rp[ky] = xb + (size_t)(yv[ky] ? yy : 0) * WW2 * CC;
  }

  _Float16* cp = cvb + ((size_t)b * 4096 + y * 64) * CC + c;
  float acc5[5] = {0.f, 0.f, 0.f, 0.f, 0.f};
  float acv = 0.f;

  #pragma unroll 5
  for (int u = 0; u < 70; ++u) {
    acc5[(u + 2) % 5] = 0.f;
    if (u < 64) {
      float c0 = yv[0] ? rp[0][u * CC] : 0.f;
      float c1 = yv[1] ? rp[1][u * CC] : 0.f;
      float c2 = yv[2] ? rp[2][u * CC] : 0.f;
      float c3 = yv[3] ? rp[3][u * CC] : 0.f;
      float c4 = yv[4] ? rp[4][u * CC] : 0.f;
      #pragma unroll
      for (int kx = 0; kx < 5; kx++) {
        acc5[(u + 7 - kx) % 5] += wgt[0 + kx] * c0 + wgt[5 + kx] * c1 +
                                  wgt[10 + kx] * c2 + wgt[15 + kx] * c3 +
                                  wgt[20 + kx] * c4;
      }
    }
    int xi = u - 2;
    if (xi >= 0 && xi < 64) {
      float cv = acc5[(u + 3) % 5];
      cp[(size_t)xi * CC] = (_Float16)cv;
      acv += cv;
    }
  }
  atomicAdd(&scv[b * CC + c], acv);
}

// ---------------------------------------------------------------------------
// Kernel C: sh sampling (validated round 5).
// ---------------------------------------------------------------------------
__global__ __launch_bounds__(256) void k_col(
    const float* __restrict__ x, const _Float16* __restrict__ offBT,
    _Float16* __restrict__ shb, float* __restrict__ ssh)
{
  __shared__ _Float16 xc[HH * CC];      // [y][c]
  const int work = (blockIdx.x & 7) * 128 + (blockIdx.x >> 3);  // 1024 blocks
  const int b = work >> 6, xi = work & 63;
  const int t = threadIdx.x;
  const int c = t;

  #pragma unroll
  for (int p = 0; p < 16; p++) {
    int yy = p * 4 + (t >> 6);
    int c4 = (t & 63) * 4;
    float4 v = *(const float4*)(x + ((size_t)(b * HH + yy) * WW2 + xi) * CC + c4);
    half4_t h = {(_Float16)v.x, (_Float16)v.y, (_Float16)v.z, (_Float16)v.w};
    *(half4_t*)(xc + yy * CC + c4) = h;
  }
  __syncthreads();

  const _Float16* obt = offBT + ((size_t)(b * WW2 + xi) * HH) * CC + c;
  _Float16* hp = shb + ((size_t)(b * HH) * WW2 + xi) * CC + c;
  float ash = 0.f;
  #pragma unroll 8
  for (int yy = 0; yy < 64; yy++) {
    float dy = (float)obt[(size_t)yy * CC];
    float ys = (float)yy + dy;
    float yf = floorf(ys);
    float wy = ys - yf;
    int yq = (int)yf;
    float u0 = (yq >= 0 && yq < HH) ? (float)xc[yq * CC + c] : 0.f;
    float u1 = (yq + 1 >= 0 && yq + 1 < HH) ? (float)xc[(yq + 1) * CC + c] : 0.f;
    float shv = (1.f - wy) * u0 + wy * u1;
    hp[(size_t)yy * WW2 * CC] = (_Float16)shv;
    ash += shv;
  }
  atomicAdd(&ssh[b * CC + c], ash);
}

// ---------------------------------------------------------------------------
// Kernel B: gating MLP (validated round 7).
// ---------------------------------------------------------------------------
__global__ __launch_bounds__(256) void k_gate(
    const float* __restrict__ ssw, const float* __restrict__ ssh, const float* __restrict__ scv,
    const float* __restrict__ Ww, const float* __restrict__ bw,
    const float* __restrict__ Wh, const float* __restrict__ bh,
    const float* __restrict__ blc,
    const float* __restrict__ fc1w, const float* __restrict__ fc1b,
    const float* __restrict__ fc2w, const float* __restrict__ fc2b,
    _Float16* __restrict__ gh, float* __restrict__ bcomb)
{
  __shared__ float sswl[CC], sshl[CC], avgl[CC], tl[64];
  const int b = blockIdx.x, tid = threadIdx.x;
  sswl[tid] = ssw[b * CC + tid];
  sshl[tid] = ssh[b * CC + tid];
  __syncthreads();

  float acc = scv[b * CC + tid];
  for (int c = 0; c < CC; c++)
    acc += sswl[c] * Ww[tid * CC + c] + sshl[c] * Wh[tid * CC + c];
  avgl[tid] = acc * (1.f / (HH * WW2)) + bw[tid] + bh[tid] + blc[tid];
  __syncthreads();

  if (tid < 64) {
    float a = fc1b[tid];
    for (int o = 0; o < CC; o++) a += avgl[o] * fc1w[tid * CC + o];
    tl[tid] = 0.5f * a * (1.f + erff(a * 0.70710678118654752f));
  }
  __syncthreads();

  float g[3];
  #pragma unroll
  for (int j = 0; j < 3; j++) {
    float a = fc2b[tid * 3 + j];
    for (int k = 0; k < 64; k++) a += tl[k] * fc2w[(tid * 3 + j) * 64 + k];
    g[j] = a;
  }
  float m = fmaxf(g[0], fmaxf(g[1], g[2]));
  float e0 = expf(g[0] - m), e1 = expf(g[1] - m), e2 = expf(g[2] - m);
  float inv = 1.f / (e0 + e1 + e2);
  float a0 = e0 * inv, a1 = e1 * inv, a2 = e2 * inv;
  gh[(0 * BB + b) * CC + tid] = (_Float16)a0;
  gh[(1 * BB + b) * CC + tid] = (_Float16)a1;
  gh[(2 * BB + b) * CC + tid] = (_Float16)a2;
  bcomb[b * CC + tid] = a0 * bw[tid] + a1 * bh[tid] + a2 * blc[tid];
}

// ---------------------------------------------------------------------------
// Kernel M: build per-batch collapsed weights (validated round 7).
// ---------------------------------------------------------------------------
__global__ __launch_bounds__(256) void k_mats(
    const _Float16* __restrict__ pf, const _Float16* __restrict__ gh,
    const _Float16* __restrict__ WwT, const _Float16* __restrict__ WhT,
    const float* __restrict__ bcomb, const float* __restrict__ pb,
    _Float16* __restrict__ Bcat, float* __restrict__ bias_out)
{
  const int blk = (blockIdx.x & 7) * 16 + (blockIdx.x >> 3);  // 128 blocks
  const int ob = blk & 3;
  const int br = (blk >> 2) & 1;
  const int b  = blk >> 3;
  const int o0 = ob * 64;
  const int tid = threadIdx.x;
  const int wid = tid >> 6, l = tid & 63;
  const int n0 = wid * 64;             // k-column block
  const int lr = l & 15;
  const int kg = (l >> 4) * 8;
  const int jr = (l >> 4) * 4;

  const _Float16* WT  = br ? WhT : WwT;
  const _Float16* ghb = gh + (size_t)(br * BB + b) * CC;

  f32x4 acc[4][4];
  #pragma unroll
  for (int mi = 0; mi < 4; mi++)
    #pragma unroll
    for (int ni = 0; ni < 4; ni++) acc[mi][ni] = (f32x4){0.f, 0.f, 0.f, 0.f};

  #pragma unroll
  for (int ks = 0; ks < 8; ks++) {
    half8 gv = *(const half8*)(ghb + kg + ks * 32);
    half8 a[4], bbv[4];
    #pragma unroll
    for (int mi = 0; mi < 4; mi++)
      a[mi] = *(const half8*)(pf + (size_t)(o0 + mi * 16 + lr) * CC + kg + ks * 32) * gv;
    #pragma unroll
    for (int ni = 0; ni < 4; ni++)
      bbv[ni] = *(const half8*)(WT + (size_t)(n0 + ni * 16 + lr) * CC + kg + ks * 32);
    #pragma unroll
    for (int mi = 0; mi < 4; mi++)
      #pragma unroll
      for (int ni = 0; ni < 4; ni++)
        acc[mi][ni] = __builtin_amdgcn_mfma_f32_16x16x32_f16(a[mi], bbv[ni], acc[mi][ni], 0, 0, 0);
  }

  #pragma unroll
  for (int ni = 0; ni < 4; ni++) {
    int kcol = n0 + ni * 16 + lr;
    #pragma unroll
    for (int mi = 0; mi < 4; mi++) {
      #pragma unroll
      for (int j = 0; j < 4; j++) {
        int o = o0 + mi * 16 + jr + j;
        Bcat[((size_t)b * CC + o) * 512 + br * 256 + kcol] = (_Float16)acc[mi][ni][j];
      }
    }
  }

  if (br == 0) {
    int o_l = tid >> 2, part = tid & 3;
    const _Float16* pr = pf + (size_t)(o0 + o_l) * CC + part * 64;
    const float* bc = bcomb + b * CC + part * 64;
    float s = 0.f;
    #pragma unroll
    for (int i = 0; i < 8; i++) {
      half8 h = *(const half8*)(pr + i * 8);
      #pragma unroll
      for (int r = 0; r < 8; r++) s += (float)h[r] * bc[i * 8 + r];
    }
    s += __shfl_xor(s, 1);
    s += __shfl_xor(s, 2);
    if (part == 0) bias_out[b * CC + o0 + o_l] = s + pb[o0 + o_l];
  }
}

// ---------------------------------------------------------------------------
// Kernel G: single K=768 GEMM (validated round 7).
// ---------------------------------------------------------------------------
#define APAD 264
__global__ __launch_bounds__(256) void k_gemm(
    const _Float16* __restrict__ swb, const _Float16* __restrict__ shb,
    const _Float16* __restrict__ cvb, const _Float16* __restrict__ Bcat,
    const _Float16* __restrict__ pf, const _Float16* __restrict__ a2h,
    const float* __restrict__ bias_out, float* __restrict__ out)
{
  __shared__ _Float16 smem[64 * APAD];  // 33,792 B

  const int work = (blockIdx.x & 7) * 128 + (blockIdx.x >> 3);  // 1024 blocks
  const int r0 = work * 64;
  const int b = work >> 6;
  const int tid = threadIdx.x;
  const int wid = tid >> 6, l = tid & 63;
  const int n0 = wid * 64;
  const int lr = l & 15;
  const int kg = (l >> 4) * 8;
  const int jr = (l >> 4) * 4;

  const _Float16* bq = Bcat + ((size_t)b * CC + n0 + lr) * 512 + kg;

  f32x4 acc[4][4];
  #pragma unroll
  for (int mi = 0; mi < 4; mi++)
    #pragma unroll
    for (int ni = 0; ni < 4; ni++) acc[mi][ni] = (f32x4){0.f, 0.f, 0.f, 0.f};

  half8 st[8];
  // stage sw
  {
    const _Float16* g = swb + (size_t)r0 * CC;
    #pragma unroll
    for (int p = 0; p < 8; p++) st[p] = *(const half8*)(g + p * 2048 + tid * 8);
    #pragma unroll
    for (int p = 0; p < 8; p++) {
      int i = p * 2048 + tid * 8;
      *(half8*)(smem + (i >> 8) * APAD + (i & 255)) = st[p];
    }
  }
  __syncthreads();
  // prefetch sh (completes during sw phase)
  {
    const _Float16* g = shb + (size_t)r0 * CC;
    #pragma unroll
    for (int p = 0; p < 8; p++) st[p] = *(const half8*)(g + p * 2048 + tid * 8);
  }
  // ---- phase A: sw, ks 0..7 ----
  #pragma unroll
  for (int ks = 0; ks < 8; ks++) {
    half8 a[4], bbv[4];
    #pragma unroll
    for (int mi = 0; mi < 4; mi++)
      a[mi] = *(const half8*)(smem + (mi * 16 + lr) * APAD + kg + ks * 32);
    #pragma unroll
    for (int ni = 0; ni < 4; ni++)
      bbv[ni] = *(const half8*)(bq + (size_t)ni * 16 * 512 + ks * 32);
    #pragma unroll
    for (int mi = 0; mi < 4; mi++)
      #pragma unroll
      for (int ni = 0; ni < 4; ni++)
        acc[mi][ni] = __builtin_amdgcn_mfma_f32_16x16x32_f16(a[mi], bbv[ni], acc[mi][ni], 0, 0, 0);
  }
  __syncthreads();
  #pragma unroll
  for (int p = 0; p < 8; p++) {
    int i = p * 2048 + tid * 8;
    *(half8*)(smem + (i >> 8) * APAD + (i & 255)) = st[p];
  }
  __syncthreads();
  // prefetch cv (completes during sh phase)
  {
    const _Float16* g = cvb + (size_t)r0 * CC;
    #pragma unroll
    for (int p = 0; p < 8; p++) st[p] = *(const half8*)(g + p * 2048 + tid * 8);
  }
  // ---- phase B: sh, ks 0..7 (Bcat cols 256..511) ----
  #pragma unroll
  for (int ks = 0; ks < 8; ks++) {
    half8 a[4], bbv[4];
    #pragma unroll
    for (int mi = 0; mi < 4; mi++)
      a[mi] = *(const half8*)(smem + (mi * 16 + lr) * APAD + kg + ks * 32);
    #pragma unroll
    for (int ni = 0; ni < 4; ni++)
      bbv[ni] = *(const half8*)(bq + (size_t)ni * 16 * 512 + 256 + ks * 32);
    #pragma unroll
    for (int mi = 0; mi < 4; mi++)
      #pragma unroll
      for (int ni = 0; ni < 4; ni++)
        acc[mi][ni] = __builtin_amdgcn_mfma_f32_16x16x32_f16(a[mi], bbv[ni], acc[mi][ni], 0, 0, 0);
  }
  __syncthreads();
  #pragma unroll
  for (int p = 0; p < 8; p++) {
    int i = p * 2048 + tid * 8;
    *(half8*)(smem + (i >> 8) * APAD + (i & 255)) = st[p];
  }
  __syncthreads();
  // ---- phase C: cv, ks 0..7, B-frag = pf * a2 on the fly ----
  const _Float16* a2b = a2h + (size_t)b * CC;
  #pragma unroll
  for (int ks = 0; ks < 8; ks++) {
    half8 a2v = *(const half8*)(a2b + kg + ks * 32);
    half8 a[4], bbv[4];
    #pragma unroll
    for (int mi = 0; mi < 4; mi++)
      a[mi] = *(const half8*)(smem + (mi * 16 + lr) * APAD + kg + ks * 32);
    #pragma unroll
    for (int ni = 0; ni < 4; ni++)
      bbv[ni] = *(const half8*)(pf + (size_t)(n0 + ni * 16 + lr) * CC + kg + ks * 32) * a2v;
    #pragma unroll
    for (int mi = 0; mi < 4; mi++)
      #pragma unroll
      for (int ni = 0; ni < 4; ni++)
        acc[mi][ni] = __builtin_amdgcn_mfma_f32_16x16x32_f16(a[mi], bbv[ni], acc[mi][ni], 0, 0, 0);
  }

  // epilogue
  #pragma unroll
  for (int ni = 0; ni < 4; ni++) {
    int col = n0 + ni * 16 + lr;
    float bo = bias_out[b * CC + col];
    #pragma unroll
    for (int mi = 0; mi < 4; mi++) {
      #pragma unroll
      for (int j = 0; j < 4; j++) {
        size_t idx = (size_t)(r0 + mi * 16 + jr + j) * CC + col;
        out[idx] = acc[mi][ni][j] + bo;
      }
    }
  }
}

// ---------------------------------------------------------------------------
extern "C" void kernel_launch(void* const* d_in, const int* in_sizes, int n_in,
                              void* d_out, int out_size, void* d_ws, size_t ws_size,
                              hipStream_t stream)
{
  const float* x    = (const float*)d_in[0];
  const float* off  = (const float*)d_in[1];
  const float* Ww   = (const float*)d_in[2];
  const float* bw   = (const float*)d_in[3];
  const float* Wh   = (const float*)d_in[4];
  const float* bh   = (const float*)d_in[5];
  const float* lw   = (const float*)d_in[6];
  const float* blc  = (const float*)d_in[7];
  const float* fc1w = (const float*)d_in[8];
  const float* fc1b = (const float*)d_in[9];
  const float* fc2w = (const float*)d_in[10];
  const float* fc2b = (const float*)d_in[11];
  const float* pw   = (const float*)d_in[12];
  const float* pb   = (const float*)d_in[13];
  float* out = (float*)d_out;

  char* ws = (char*)d_ws;
  // ws regions, all disjoint (no aliasing; footprint 138.6 MB, proven
  // available in rounds 9-12):
  //   shb   @  0   (32M)  k_col -> k_gemm
  //   cvb   @ 32M  (32M)  k_conv -> k_gemm
  //   offBT @ 64M  (32M)  k_transB -> k_col
  //   swb   @ 96M  (32M)  k_transA -> k_gemm
  //   Bcat  @128M  ( 4M)  k_mats -> k_gemm
  //   pf/gh/bcomb/bias_out tail
  _Float16* shb   = (_Float16*)(ws + 0);
  _Float16* cvb   = (_Float16*)(ws + 33554432);
  _Float16* offBT = (_Float16*)(ws + 67108864);
  _Float16* swb   = (_Float16*)(ws + 100663296);
  _Float16* Bcat  = (_Float16*)(ws + 134217728);  // 4 MiB
  _Float16* pf    = (_Float16*)(ws + 138412032);  // 131,072 B
  _Float16* gh    = (_Float16*)(ws + 138543104);  //  24,576 B
  float* bcomb    = (float*)(ws + 138567680);     //  16,384 B
  float* bias_out = (float*)(ws + 138584064);     //  16,384 B
  // d_out scratch (consumed before k_gemm writes out):
  _Float16* WwT = (_Float16*)((char*)d_out + 0);        // 131,072 B
  _Float16* WhT = (_Float16*)((char*)d_out + 131072);   // 131,072 B
  float* sums   = (float*)((char*)d_out + 262144);      //  49,152 B
  float* ssw = sums, *ssh = sums + 4096, *scv = sums + 8192;

  k_pre<<<112, 256, 0, stream>>>(Ww, Wh, pw, WwT, WhT, pf, sums);
  k_transB<<<4096, 256, 0, stream>>>(off, offBT);
  k_col<<<BB * WW2, 256, 0, stream>>>(x, offBT, shb, ssh);
  k_transA<<<4096, 256, 0, stream>>>(x, off, swb, ssw);
  k_conv<<<BB * HH, 256, 0, stream>>>(x, lw, cvb, scv);
  k_gate<<<BB, 256, 0, stream>>>(ssw, ssh, scv, Ww, bw, Wh, bh, blc,
                                 fc1w, fc1b, fc2w, fc2b, gh, bcomb);
  k_mats<<<128, 256, 0, stream>>>(pf, gh, WwT, WhT, bcomb, pb, Bcat, bias_out);
  k_gemm<<<1024, 256, 0, stream>>>(swb, shb, cvb, Bcat, pf, gh + 2 * BB * CC,
                                   bias_out, out);
}